// Round 15
// baseline (393.343 us; speedup 1.0000x reference)
//
#include <hip/hip_runtime.h>
#include <math.h>

#define HID 128
#define NGRAPH 4

typedef int idx_t;
typedef float f32x4 __attribute__((ext_vector_type(4)));
typedef _Float16 h8 __attribute__((ext_vector_type(8)));

// async 16B global->LDS DMA (no VGPR round-trip)
#define GLD16(gsrc, ldst)                                                  \
  __builtin_amdgcn_global_load_lds(                                        \
      (const __attribute__((address_space(1))) void*)(gsrc),               \
      (__attribute__((address_space(3))) void*)(ldst), 16, 0, 0)

// ---------------- degree histogram ----------------
__global__ __launch_bounds__(256) void k_count(const idx_t* __restrict__ dst,
                                               int* __restrict__ cnt, int E) {
  int e = blockIdx.x * 256 + threadIdx.x;
  if (e < E) atomicAdd(&cnt[dst[e]], 1);
}

// ---------------- hierarchical exclusive scan ----------------
#define SC 1024
__global__ __launch_bounds__(256) void k_scan1(const int* __restrict__ cnt,
                                               int* __restrict__ bsum, int n) {
  __shared__ int sh[256];
  int base = blockIdx.x * SC + threadIdx.x * 4;
  int s = 0;
#pragma unroll
  for (int j = 0; j < 4; ++j) { int i = base + j; if (i < n) s += cnt[i]; }
  sh[threadIdx.x] = s;
  __syncthreads();
  for (int o = 128; o > 0; o >>= 1) {
    if (threadIdx.x < o) sh[threadIdx.x] += sh[threadIdx.x + o];
    __syncthreads();
  }
  if (threadIdx.x == 0) bsum[blockIdx.x] = sh[0];
}

__global__ __launch_bounds__(64) void k_scan2(const int* __restrict__ bsum,
                                              int* __restrict__ boff,
                                              int* __restrict__ off, int nb, int n) {
  int lane = threadIdx.x;
  int v = (lane < nb) ? bsum[lane] : 0;
  for (int d = 1; d < 64; d <<= 1) {
    int t = __shfl_up(v, d);
    if (lane >= d) v += t;
  }
  int ex = __shfl_up(v, 1);
  if (lane == 0) ex = 0;
  if (lane < nb) boff[lane] = ex;
  if (lane == nb - 1) off[n] = v;
}

__global__ __launch_bounds__(256) void k_scan3(const int* __restrict__ cnt,
                                               const int* __restrict__ boff,
                                               int* __restrict__ off,
                                               float* __restrict__ dinv, int n) {
  __shared__ int sh[256];
  int base = blockIdx.x * SC + threadIdx.x * 4;
  int c[4];
  int s = 0;
#pragma unroll
  for (int j = 0; j < 4; ++j) {
    int i = base + j;
    c[j] = (i < n) ? cnt[i] : 0;
    s += c[j];
  }
  sh[threadIdx.x] = s;
  __syncthreads();
  for (int o = 1; o < 256; o <<= 1) {
    int t = (threadIdx.x >= (unsigned)o) ? sh[threadIdx.x - o] : 0;
    __syncthreads();
    sh[threadIdx.x] += t;
    __syncthreads();
  }
  int ex = sh[threadIdx.x] - s + boff[blockIdx.x];
#pragma unroll
  for (int j = 0; j < 4; ++j) {
    int i = base + j;
    if (i < n) {
      off[i] = ex;
      dinv[i] = 1.0f / sqrtf((float)c[j] + 1.0f);
      ex += c[j];
    }
  }
}

// ---------------- CSR fill: packed (src, weight) per edge ----------------
__global__ __launch_bounds__(256) void k_fill(const idx_t* __restrict__ src,
                                              const idx_t* __restrict__ dst,
                                              const int* __restrict__ off,
                                              const float* __restrict__ dinv,
                                              int* __restrict__ fillc,
                                              int2* __restrict__ edata, int E) {
  int e = blockIdx.x * 256 + threadIdx.x;
  if (e < E) {
    int s = src[e], d = dst[e];
    int p = atomicAdd(&fillc[d], 1);
    float w = dinv[s] * dinv[d];
    edata[off[d] + p] = make_int2(s, __float_as_int(w));
  }
}

// ---------------- per-segment src-sort (perf hint for L2 locality) --------
// One wave per node; 64-lane bitonic sort of (src<<32|w) keys. All waves
// then walk their neighbor lists in src order at the same rank-rate, so
// concurrent gathers cluster in a sliding src window (L2-resident).
// deg>64 segments are left unsorted (correctness unaffected).
__global__ __launch_bounds__(256) void k_sort(const int* __restrict__ off,
                                              int2* __restrict__ edata, int n) {
  int v = blockIdx.x * 4 + (threadIdx.x >> 6);
  if (v >= n) return;
  int lane = threadIdx.x & 63;
  int j0 = off[v];
  int deg = off[v + 1] - j0;
  if (deg <= 1 || deg > 64) return;
  unsigned long long u = ~0ull;
  if (lane < deg) {
    int2 e = edata[j0 + lane];
    u = ((unsigned long long)(unsigned)e.x << 32) | (unsigned)e.y;
  }
#pragma unroll
  for (int k = 2; k <= 64; k <<= 1) {
#pragma unroll
    for (int j = k >> 1; j > 0; j >>= 1) {
      unsigned long long p = __shfl_xor(u, j);
      bool lower = (lane & j) == 0;
      bool asc = (lane & k) == 0;
      unsigned long long mn = (u < p) ? u : p;
      unsigned long long mx = (u < p) ? p : u;
      u = (lower == asc) ? mn : mx;
    }
  }
  if (lane < deg)
    edata[j0 + lane] = make_int2((int)(u >> 32), (int)(u & 0xFFFFFFFFull));
}

// ---------------- W split, fragment-ordered ------------------------------
__global__ __launch_bounds__(256) void k_wsplitf(const float* __restrict__ W,
                                                 _Float16* __restrict__ Wh,
                                                 _Float16* __restrict__ Wl, int K) {
  int i = blockIdx.x * 256 + threadIdx.x;
  if (i >= K * HID) return;
  int j = i & 7, lane = (i >> 3) & 63, ni = (i >> 9) & 7, t = i >> 12;
  int k = t * 32 + (lane >> 4) * 8 + j;
  int col = ni * 16 + (lane & 15);
  float f = W[(size_t)k * HID + col];
  _Float16 h = (_Float16)f;
  Wh[i] = h;
  Wl[i] = (_Float16)(f - (float)h);
}

// ---------------- global_load_lds dbuf MFMA GEMM, counted vmcnt ------------
template <int K, bool F32>
__global__ __launch_bounds__(256) void k_gemm8(const void* __restrict__ Xv,
                                               const _Float16* __restrict__ Wfh,
                                               const _Float16* __restrict__ Wfl,
                                               _Float16* __restrict__ Y16, int M) {
  constexpr int NT = K / 32;
  __shared__ __align__(16) char smem[49152];   // A 2x8K | Bh 2x8K | Bl 2x8K
  char* Abuf = smem;
  char* Bhbuf = smem + 16384;
  char* Blbuf = smem + 32768;
  const int tid = threadIdx.x;
  const int wid = tid >> 6, lane = tid & 63;
  const int lrow = lane & 15, kg = lane >> 4;
  const int row0 = blockIdx.x * 64;

  auto stage = [&](int buf, int t) {
    const int k0 = t * 32;
    char* dA = Abuf + buf * 8192;
    if (F32) {
      const float* X = (const float*)Xv;
#pragma unroll
      for (int p = 0; p < 2; ++p) {
        int q = tid * 16 + p * 4096;
        int r = q >> 7, b = q & 127;
        int rg = row0 + r; if (rg >= M) rg = M - 1;
        int bs = b ^ ((r & 7) << 4);
        GLD16((const char*)&X[(size_t)rg * K + k0] + bs, dA + q);
      }
    } else {
      const _Float16* X = (const _Float16*)Xv;
      int q = tid * 16;
      int r = q >> 6, b = q & 63;
      int rg = row0 + r; if (rg >= M) rg = M - 1;
      int bs = b ^ ((r & 3) << 4);
      GLD16((const char*)&X[(size_t)rg * K + k0] + bs, dA + q);
    }
    const char* sBh = (const char*)(Wfh + (size_t)t * 4096);
    const char* sBl = (const char*)(Wfl + (size_t)t * 4096);
    char* dBh = Bhbuf + buf * 8192;
    char* dBl = Blbuf + buf * 8192;
    GLD16(sBh + tid * 16, dBh + tid * 16);
    GLD16(sBh + tid * 16 + 4096, dBh + tid * 16 + 4096);
    GLD16(sBl + tid * 16, dBl + tid * 16);
    GLD16(sBl + tid * 16 + 4096, dBl + tid * 16 + 4096);
  };

  f32x4 acc[8] = {};
  stage(0, 0);
  if (NT > 1) stage(1, 1);
  int buf = 0;
  const int row = wid * 16 + lrow;
  for (int t = 0; t < NT; ++t) {
    if (t + 1 < NT) {
      if (F32) asm volatile("s_waitcnt vmcnt(6)" ::: "memory");
      else     asm volatile("s_waitcnt vmcnt(5)" ::: "memory");
    } else {
      asm volatile("s_waitcnt vmcnt(0)" ::: "memory");
    }
    __builtin_amdgcn_sched_barrier(0);
    __builtin_amdgcn_s_barrier();
    __builtin_amdgcn_sched_barrier(0);

    h8 ah, al;
    if (F32) {
      const char* pA = Abuf + buf * 8192 + row * 128;
      int sw_ = (row & 7) << 4;
      f32x4 a0 = *(const f32x4*)(pA + ((kg * 32) ^ sw_));
      f32x4 a1 = *(const f32x4*)(pA + ((kg * 32 + 16) ^ sw_));
      float tf[8] = {a0[0], a0[1], a0[2], a0[3], a1[0], a1[1], a1[2], a1[3]};
#pragma unroll
      for (int j = 0; j < 8; ++j) {
        _Float16 hh = (_Float16)tf[j];
        ah[j] = hh;
        al[j] = (_Float16)(tf[j] - (float)hh);
      }
    } else {
      const char* pA = Abuf + buf * 8192 + row * 64;
      ah = *(const h8*)(pA + ((kg * 16) ^ ((row & 3) << 4)));
    }
    const char* pBh = Bhbuf + buf * 8192;
    const char* pBl = Blbuf + buf * 8192;
#pragma unroll
    for (int ni = 0; ni < 8; ++ni) {
      h8 bh = *(const h8*)(pBh + (ni * 64 + lane) * 16);
      h8 bl = *(const h8*)(pBl + (ni * 64 + lane) * 16);
      acc[ni] = __builtin_amdgcn_mfma_f32_16x16x32_f16(ah, bh, acc[ni], 0, 0, 0);
      if (F32)
        acc[ni] = __builtin_amdgcn_mfma_f32_16x16x32_f16(al, bh, acc[ni], 0, 0, 0);
      acc[ni] = __builtin_amdgcn_mfma_f32_16x16x32_f16(ah, bl, acc[ni], 0, 0, 0);
    }
    __builtin_amdgcn_sched_barrier(0);
    __builtin_amdgcn_s_barrier();
    __builtin_amdgcn_sched_barrier(0);
    if (t + 2 < NT) stage(buf, t + 2);
    buf ^= 1;
  }
#pragma unroll
  for (int ni = 0; ni < 8; ++ni)
#pragma unroll
    for (int rr = 0; rr < 4; ++rr) {
      int grow = row0 + wid * 16 + kg * 4 + rr;
      if (grow < M)
        Y16[(size_t)grow * HID + ni * 16 + lrow] = (_Float16)acc[ni][rr];
    }
}

// ---------------- gather-aggregate (fp16) + bias + ReLU --------------------
// One wave per node; 8 groups of 8 lanes; each lane covers 16 features (32B).
// With src-sorted lists, the 8 groups' concurrent gathers (ranks 8i..8i+7)
// sit in one src-quantile window -> L2-resident.
__global__ __launch_bounds__(256) void k_agg16(const _Float16* __restrict__ xh,
                                               const float* __restrict__ dinv,
                                               const int* __restrict__ off,
                                               const int2* __restrict__ edata,
                                               const float* __restrict__ bias,
                                               _Float16* __restrict__ hout, int n) {
  int v = blockIdx.x * 4 + (threadIdx.x >> 6);
  if (v >= n) return;
  int lane = threadIdx.x & 63;
  int grp = lane >> 3, gl = lane & 7;
  int fb = gl * 16;
  float acc[16] = {0.f, 0.f, 0.f, 0.f, 0.f, 0.f, 0.f, 0.f,
                   0.f, 0.f, 0.f, 0.f, 0.f, 0.f, 0.f, 0.f};
  int j0 = off[v], j1 = off[v + 1];
  for (int j = j0 + grp; j < j1; j += 8) {
    int2 e = edata[j];
    float w = __int_as_float(e.y);
    h8 m0 = *(const h8*)&xh[(size_t)e.x * HID + fb];
    h8 m1 = *(const h8*)&xh[(size_t)e.x * HID + fb + 8];
#pragma unroll
    for (int q = 0; q < 8; ++q) {
      acc[q] = fmaf(w, (float)m0[q], acc[q]);
      acc[8 + q] = fmaf(w, (float)m1[q], acc[8 + q]);
    }
  }
#pragma unroll
  for (int q = 0; q < 16; ++q) {
    acc[q] += __shfl_xor(acc[q], 8);
    acc[q] += __shfl_xor(acc[q], 16);
    acc[q] += __shfl_xor(acc[q], 32);
  }
  if (grp == 0) {
    float dv = dinv[v], dv2 = dv * dv;
    h8 s0 = *(const h8*)&xh[(size_t)v * HID + fb];
    h8 s1 = *(const h8*)&xh[(size_t)v * HID + fb + 8];
    h8 o0, o1;
#pragma unroll
    for (int q = 0; q < 8; ++q) {
      float a0 = fmaxf(fmaf(dv2, (float)s0[q], acc[q]) + bias[fb + q], 0.f);
      float a1 = fmaxf(fmaf(dv2, (float)s1[q], acc[8 + q]) + bias[fb + 8 + q], 0.f);
      o0[q] = (_Float16)a0;
      o1[q] = (_Float16)a1;
    }
    *(h8*)&hout[(size_t)v * HID + fb] = o0;
    *(h8*)&hout[(size_t)v * HID + fb + 8] = o1;
  }
}

// ---------------- per-graph node counts ----------------
__global__ __launch_bounds__(256) void k_gcnt(const idx_t* __restrict__ batch,
                                              int* __restrict__ gcnt, int n) {
  __shared__ int h[NGRAPH];
  int tid = threadIdx.x;
  if (tid < NGRAPH) h[tid] = 0;
  __syncthreads();
  int i = blockIdx.x * 256 + tid;
  if (i < n) atomicAdd(&h[batch[i]], 1);
  __syncthreads();
  if (tid < NGRAPH && h[tid]) atomicAdd(&gcnt[tid], h[tid]);
}

// ---------------- segment max+sum pooling (fp16 input, batch sorted) -------
__global__ __launch_bounds__(128) void k_pool(const _Float16* __restrict__ h,
                                              const idx_t* __restrict__ batch,
                                              float* __restrict__ gmax,
                                              float* __restrict__ gsum, int n) {
  int f = threadIdx.x;
  int v0 = blockIdx.x * 128;
  int cur = -1;
  float mx = 0.f, sm = 0.f;
  for (int i = 0; i < 128; ++i) {
    int v = v0 + i;
    if (v >= n) break;
    int g = batch[v];
    if (g != cur) {
      if (cur >= 0) {
        atomicMax((int*)&gmax[cur * HID + f], __float_as_int(mx));  // h>=0
        atomicAdd(&gsum[cur * HID + f], sm);
      }
      cur = g; mx = 0.f; sm = 0.f;
    }
    float val = (float)h[(size_t)v * HID + f];
    mx = fmaxf(mx, val);
    sm += val;
  }
  if (cur >= 0) {
    atomicMax((int*)&gmax[cur * HID + f], __float_as_int(mx));
    atomicAdd(&gsum[cur * HID + f], sm);
  }
}

// ---------------- tiny MLP head (one block) ----------------
__global__ __launch_bounds__(256) void k_mlp(const float* __restrict__ gmax,
                                             const float* __restrict__ gsum,
                                             const int* __restrict__ gcnt,
                                             const float* __restrict__ Wl1,
                                             const float* __restrict__ bl1,
                                             const float* __restrict__ Wl2,
                                             const float* __restrict__ bl2,
                                             const float* __restrict__ Wl3,
                                             const float* __restrict__ bl3,
                                             float* __restrict__ out) {
  __shared__ float G[NGRAPH][2 * HID];
  __shared__ float H1[NGRAPH][HID];
  __shared__ float H2[NGRAPH][HID / 2];
  int t = threadIdx.x;
  for (int i = t; i < NGRAPH * 2 * HID; i += 256) {
    int gi = i >> 8, j = i & 255;
    float val;
    if (j < HID) val = gmax[gi * HID + j];
    else val = gsum[gi * HID + (j - HID)] / fmaxf((float)gcnt[gi], 1.0f);
    G[gi][j] = val;
  }
  __syncthreads();
  for (int i = t; i < NGRAPH * HID; i += 256) {
    int gi = i >> 7, j = i & 127;
    float a = bl1[j];
    for (int k = 0; k < 2 * HID; ++k) a = fmaf(G[gi][k], Wl1[k * HID + j], a);
    H1[gi][j] = fmaxf(a, 0.f);
  }
  __syncthreads();
  {
    int gi = t >> 6, j = t & 63;
    float a = bl2[j];
    for (int k = 0; k < HID; ++k) a = fmaf(H1[gi][k], Wl2[k * 64 + j], a);
    H2[gi][j] = fmaxf(a, 0.f);
  }
  __syncthreads();
  if (t < NGRAPH) {
    float a = bl3[0];
    for (int k = 0; k < 64; ++k) a = fmaf(H2[t][k], Wl3[k], a);
    out[t] = fminf(a, 5.0f);
  }
}

extern "C" void kernel_launch(void* const* d_in, const int* in_sizes, int n_in,
                              void* d_out, int out_size, void* d_ws, size_t ws_size,
                              hipStream_t stream) {
  const float* x   = (const float*)d_in[0];
  const idx_t* ei  = (const idx_t*)d_in[1];
  const idx_t* bat = (const idx_t*)d_in[2];
  const float* W0 = (const float*)d_in[3];  const float* b0 = (const float*)d_in[4];
  const float* W1 = (const float*)d_in[5];  const float* b1 = (const float*)d_in[6];
  const float* W2 = (const float*)d_in[7];  const float* b2 = (const float*)d_in[8];
  const float* Wl1 = (const float*)d_in[9];  const float* bl1 = (const float*)d_in[10];
  const float* Wl2 = (const float*)d_in[11]; const float* bl2 = (const float*)d_in[12];
  const float* Wl3 = (const float*)d_in[13]; const float* bl3 = (const float*)d_in[14];
  float* out = (float*)d_out;

  const int N = in_sizes[2];
  const int E = in_sizes[1] / 2;
  const idx_t* srcv = ei;
  const idx_t* dstv = ei + E;
  const int nb = (N + SC - 1) / SC;

  char* ws = (char*)d_ws;
  size_t o = 0;
  auto alloc = [&](size_t bytes) -> void* {
    void* p = ws + o;
    o = (o + bytes + 255) & ~(size_t)255;
    return p;
  };
  _Float16* xh  = (_Float16*)alloc((size_t)N * HID * 2);  // GEMM out (gathered)
  _Float16* h16 = (_Float16*)alloc((size_t)N * HID * 2);  // agg out
  float* dinv = (float*)alloc((size_t)N * 4);
  int* cnt    = (int*)alloc((size_t)N * 4);
  int* off    = (int*)alloc((size_t)(N + 1) * 4);
  int* fillc  = (int*)alloc((size_t)N * 4);
  int2* edata = (int2*)alloc((size_t)E * 8);
  int* bsum   = (int*)alloc(64 * 4);
  int* boff   = (int*)alloc(64 * 4);
  _Float16* Wh0 = (_Float16*)alloc((size_t)1024 * HID * 2);
  _Float16* Wl0 = (_Float16*)alloc((size_t)1024 * HID * 2);
  _Float16* Wh1 = (_Float16*)alloc((size_t)HID * HID * 2);
  _Float16* Wlo1 = (_Float16*)alloc((size_t)HID * HID * 2);
  _Float16* Wh2 = (_Float16*)alloc((size_t)HID * HID * 2);
  _Float16* Wlo2 = (_Float16*)alloc((size_t)HID * HID * 2);
  float* gmax = (float*)alloc(NGRAPH * HID * 4);
  float* gsum = (float*)alloc(NGRAPH * HID * 4);
  int* gcnt   = (int*)alloc(NGRAPH * 4);

  hipMemsetAsync(cnt, 0, (size_t)N * 4, stream);
  hipMemsetAsync(fillc, 0, (size_t)N * 4, stream);
  hipMemsetAsync(gmax, 0, NGRAPH * HID * 4, stream);
  hipMemsetAsync(gsum, 0, NGRAPH * HID * 4, stream);
  hipMemsetAsync(gcnt, 0, NGRAPH * 4, stream);

  // weight splits, fragment-ordered (tiny)
  k_wsplitf<<<(1024 * HID + 255) / 256, 256, 0, stream>>>(W0, Wh0, Wl0, 1024);
  k_wsplitf<<<(HID * HID + 255) / 256, 256, 0, stream>>>(W1, Wh1, Wlo1, HID);
  k_wsplitf<<<(HID * HID + 255) / 256, 256, 0, stream>>>(W2, Wh2, Wlo2, HID);

  // CSR build (+ per-segment src sort for gather locality)
  k_count<<<(E + 255) / 256, 256, 0, stream>>>(dstv, cnt, E);
  k_scan1<<<nb, 256, 0, stream>>>(cnt, bsum, N);
  k_scan2<<<1, 64, 0, stream>>>(bsum, boff, off, nb, N);
  k_scan3<<<nb, 256, 0, stream>>>(cnt, boff, off, dinv, N);
  k_fill<<<(E + 255) / 256, 256, 0, stream>>>(srcv, dstv, off, dinv, fillc, edata, E);
  k_sort<<<(N + 3) / 4, 256, 0, stream>>>(off, edata, N);

  const int gblk = (N + 63) / 64;   // 782 blocks, 4 waves each (M-split)
  const int ablk = (N + 3) / 4;
  // layer 0: 1024 -> 128 (fp32 in, 3-pass)
  k_gemm8<1024, true><<<gblk, 256, 0, stream>>>(x, Wh0, Wl0, xh, N);
  k_agg16<<<ablk, 256, 0, stream>>>(xh, dinv, off, edata, b0, h16, N);
  // layer 1 (fp16 in, 2-pass)
  k_gemm8<HID, false><<<gblk, 256, 0, stream>>>(h16, Wh1, Wlo1, xh, N);
  k_agg16<<<ablk, 256, 0, stream>>>(xh, dinv, off, edata, b1, h16, N);
  // layer 2
  k_gemm8<HID, false><<<gblk, 256, 0, stream>>>(h16, Wh2, Wlo2, xh, N);
  k_agg16<<<ablk, 256, 0, stream>>>(xh, dinv, off, edata, b2, h16, N);

  // pooling + head
  k_gcnt<<<(N + 255) / 256, 256, 0, stream>>>(bat, gcnt, N);
  k_pool<<<(N + 127) / 128, 128, 0, stream>>>(h16, bat, gmax, gsum, N);
  k_mlp<<<1, 256, 0, stream>>>(gmax, gsum, gcnt, Wl1, bl1, Wl2, bl2, Wl3, bl3, out);
}

// Round 16
// 362.657 us; speedup vs baseline: 1.0846x; 1.0846x over previous
//
#include <hip/hip_runtime.h>
#include <math.h>

#define HID 128
#define NGRAPH 4

typedef int idx_t;
typedef float f32x4 __attribute__((ext_vector_type(4)));
typedef _Float16 h8 __attribute__((ext_vector_type(8)));

// async 16B global->LDS DMA (no VGPR round-trip)
#define GLD16(gsrc, ldst)                                                  \
  __builtin_amdgcn_global_load_lds(                                        \
      (const __attribute__((address_space(1))) void*)(gsrc),               \
      (__attribute__((address_space(3))) void*)(ldst), 16, 0, 0)

// ---------------- degree histogram ----------------
__global__ __launch_bounds__(256) void k_count(const idx_t* __restrict__ dst,
                                               int* __restrict__ cnt, int E) {
  int e = blockIdx.x * 256 + threadIdx.x;
  if (e < E) atomicAdd(&cnt[dst[e]], 1);
}

// ---------------- hierarchical exclusive scan ----------------
#define SC 1024
__global__ __launch_bounds__(256) void k_scan1(const int* __restrict__ cnt,
                                               int* __restrict__ bsum, int n) {
  __shared__ int sh[256];
  int base = blockIdx.x * SC + threadIdx.x * 4;
  int s = 0;
#pragma unroll
  for (int j = 0; j < 4; ++j) { int i = base + j; if (i < n) s += cnt[i]; }
  sh[threadIdx.x] = s;
  __syncthreads();
  for (int o = 128; o > 0; o >>= 1) {
    if (threadIdx.x < o) sh[threadIdx.x] += sh[threadIdx.x + o];
    __syncthreads();
  }
  if (threadIdx.x == 0) bsum[blockIdx.x] = sh[0];
}

__global__ __launch_bounds__(64) void k_scan2(const int* __restrict__ bsum,
                                              int* __restrict__ boff,
                                              int* __restrict__ off, int nb, int n) {
  int lane = threadIdx.x;
  int v = (lane < nb) ? bsum[lane] : 0;
  for (int d = 1; d < 64; d <<= 1) {
    int t = __shfl_up(v, d);
    if (lane >= d) v += t;
  }
  int ex = __shfl_up(v, 1);
  if (lane == 0) ex = 0;
  if (lane < nb) boff[lane] = ex;
  if (lane == nb - 1) off[n] = v;
}

__global__ __launch_bounds__(256) void k_scan3(const int* __restrict__ cnt,
                                               const int* __restrict__ boff,
                                               int* __restrict__ off,
                                               float* __restrict__ dinv, int n) {
  __shared__ int sh[256];
  int base = blockIdx.x * SC + threadIdx.x * 4;
  int c[4];
  int s = 0;
#pragma unroll
  for (int j = 0; j < 4; ++j) {
    int i = base + j;
    c[j] = (i < n) ? cnt[i] : 0;
    s += c[j];
  }
  sh[threadIdx.x] = s;
  __syncthreads();
  for (int o = 1; o < 256; o <<= 1) {
    int t = (threadIdx.x >= (unsigned)o) ? sh[threadIdx.x - o] : 0;
    __syncthreads();
    sh[threadIdx.x] += t;
    __syncthreads();
  }
  int ex = sh[threadIdx.x] - s + boff[blockIdx.x];
#pragma unroll
  for (int j = 0; j < 4; ++j) {
    int i = base + j;
    if (i < n) {
      off[i] = ex;
      dinv[i] = 1.0f / sqrtf((float)c[j] + 1.0f);
      ex += c[j];
    }
  }
}

// ---------------- CSR fill: packed (src, weight) per edge ----------------
__global__ __launch_bounds__(256) void k_fill(const idx_t* __restrict__ src,
                                              const idx_t* __restrict__ dst,
                                              const int* __restrict__ off,
                                              const float* __restrict__ dinv,
                                              int* __restrict__ fillc,
                                              int2* __restrict__ edata, int E) {
  int e = blockIdx.x * 256 + threadIdx.x;
  if (e < E) {
    int s = src[e], d = dst[e];
    int p = atomicAdd(&fillc[d], 1);
    float w = dinv[s] * dinv[d];
    edata[off[d] + p] = make_int2(s, __float_as_int(w));
  }
}

// ---------------- W split, fragment-ordered ------------------------------
// Wh/Wl[i], i = ((t*8 + ni)*64 + lane)*8 + j  holds
// W[k = t*32 + (lane>>4)*8 + j][col = ni*16 + (lane&15)] as fp16 hi/lo.
// Per K-step t the 8KB chunk is contiguous -> linear LDS staging matches
// the per-lane b128 read pattern exactly.
__global__ __launch_bounds__(256) void k_wsplitf(const float* __restrict__ W,
                                                 _Float16* __restrict__ Wh,
                                                 _Float16* __restrict__ Wl, int K) {
  int i = blockIdx.x * 256 + threadIdx.x;
  if (i >= K * HID) return;
  int j = i & 7, lane = (i >> 3) & 63, ni = (i >> 9) & 7, t = i >> 12;
  int k = t * 32 + (lane >> 4) * 8 + j;
  int col = ni * 16 + (lane & 15);
  float f = W[(size_t)k * HID + col];
  _Float16 h = (_Float16)f;
  Wh[i] = h;
  Wl[i] = (_Float16)(f - (float)h);
}

// ---------------- global_load_lds dbuf MFMA GEMM, counted vmcnt ------------
// Y16[M][128] = X[M][K] @ W[K][128].  BM=64, BK=32; 4 waves x 16 rows.
// Raw s_barrier + inline-asm counted s_waitcnt vmcnt(N): next stage's DMA
// loads stay in flight ACROSS the barrier (T4 pattern); only the consumed
// buffer's loads are waited.
template <int K, bool F32>
__global__ __launch_bounds__(256) void k_gemm8(const void* __restrict__ Xv,
                                               const _Float16* __restrict__ Wfh,
                                               const _Float16* __restrict__ Wfl,
                                               _Float16* __restrict__ Y16, int M) {
  constexpr int NT = K / 32;
  __shared__ __align__(16) char smem[49152];   // A 2x8K | Bh 2x8K | Bl 2x8K
  char* Abuf = smem;
  char* Bhbuf = smem + 16384;
  char* Blbuf = smem + 32768;
  const int tid = threadIdx.x;
  const int wid = tid >> 6, lane = tid & 63;
  const int lrow = lane & 15, kg = lane >> 4;
  const int row0 = blockIdx.x * 64;

  auto stage = [&](int buf, int t) {
    const int k0 = t * 32;
    char* dA = Abuf + buf * 8192;
    if (F32) {
      const float* X = (const float*)Xv;
#pragma unroll
      for (int p = 0; p < 2; ++p) {
        int q = tid * 16 + p * 4096;
        int r = q >> 7, b = q & 127;
        int rg = row0 + r; if (rg >= M) rg = M - 1;
        int bs = b ^ ((r & 7) << 4);
        GLD16((const char*)&X[(size_t)rg * K + k0] + bs, dA + q);
      }
    } else {
      const _Float16* X = (const _Float16*)Xv;
      int q = tid * 16;
      int r = q >> 6, b = q & 63;
      int rg = row0 + r; if (rg >= M) rg = M - 1;
      int bs = b ^ ((r & 3) << 4);
      GLD16((const char*)&X[(size_t)rg * K + k0] + bs, dA + q);
    }
    const char* sBh = (const char*)(Wfh + (size_t)t * 4096);
    const char* sBl = (const char*)(Wfl + (size_t)t * 4096);
    char* dBh = Bhbuf + buf * 8192;
    char* dBl = Blbuf + buf * 8192;
    GLD16(sBh + tid * 16, dBh + tid * 16);
    GLD16(sBh + tid * 16 + 4096, dBh + tid * 16 + 4096);
    GLD16(sBl + tid * 16, dBl + tid * 16);
    GLD16(sBl + tid * 16 + 4096, dBl + tid * 16 + 4096);
  };

  f32x4 acc[8] = {};
  stage(0, 0);
  if (NT > 1) stage(1, 1);
  int buf = 0;
  const int row = wid * 16 + lrow;
  for (int t = 0; t < NT; ++t) {
    if (t + 1 < NT) {
      if (F32) asm volatile("s_waitcnt vmcnt(6)" ::: "memory");
      else     asm volatile("s_waitcnt vmcnt(5)" ::: "memory");
    } else {
      asm volatile("s_waitcnt vmcnt(0)" ::: "memory");
    }
    __builtin_amdgcn_sched_barrier(0);
    __builtin_amdgcn_s_barrier();
    __builtin_amdgcn_sched_barrier(0);

    h8 ah, al;
    if (F32) {
      const char* pA = Abuf + buf * 8192 + row * 128;
      int sw_ = (row & 7) << 4;
      f32x4 a0 = *(const f32x4*)(pA + ((kg * 32) ^ sw_));
      f32x4 a1 = *(const f32x4*)(pA + ((kg * 32 + 16) ^ sw_));
      float tf[8] = {a0[0], a0[1], a0[2], a0[3], a1[0], a1[1], a1[2], a1[3]};
#pragma unroll
      for (int j = 0; j < 8; ++j) {
        _Float16 hh = (_Float16)tf[j];
        ah[j] = hh;
        al[j] = (_Float16)(tf[j] - (float)hh);
      }
    } else {
      const char* pA = Abuf + buf * 8192 + row * 64;
      ah = *(const h8*)(pA + ((kg * 16) ^ ((row & 3) << 4)));
    }
    const char* pBh = Bhbuf + buf * 8192;
    const char* pBl = Blbuf + buf * 8192;
#pragma unroll
    for (int ni = 0; ni < 8; ++ni) {
      h8 bh = *(const h8*)(pBh + (ni * 64 + lane) * 16);
      h8 bl = *(const h8*)(pBl + (ni * 64 + lane) * 16);
      acc[ni] = __builtin_amdgcn_mfma_f32_16x16x32_f16(ah, bh, acc[ni], 0, 0, 0);
      if (F32)
        acc[ni] = __builtin_amdgcn_mfma_f32_16x16x32_f16(al, bh, acc[ni], 0, 0, 0);
      acc[ni] = __builtin_amdgcn_mfma_f32_16x16x32_f16(ah, bl, acc[ni], 0, 0, 0);
    }
    __builtin_amdgcn_sched_barrier(0);
    __builtin_amdgcn_s_barrier();
    __builtin_amdgcn_sched_barrier(0);
    if (t + 2 < NT) stage(buf, t + 2);
    buf ^= 1;
  }
#pragma unroll
  for (int ni = 0; ni < 8; ++ni)
#pragma unroll
    for (int rr = 0; rr < 4; ++rr) {
      int grow = row0 + wid * 16 + kg * 4 + rr;
      if (grow < M)
        Y16[(size_t)grow * HID + ni * 16 + lrow] = (_Float16)acc[ni][rr];
    }
}

// ---------------- gather-aggregate (fp16) + bias + ReLU --------------------
// One wave per node; 8 groups of 8 lanes; each lane covers 16 features (32B).
__global__ __launch_bounds__(256) void k_agg16(const _Float16* __restrict__ xh,
                                               const float* __restrict__ dinv,
                                               const int* __restrict__ off,
                                               const int2* __restrict__ edata,
                                               const float* __restrict__ bias,
                                               _Float16* __restrict__ hout, int n) {
  int v = blockIdx.x * 4 + (threadIdx.x >> 6);
  if (v >= n) return;
  int lane = threadIdx.x & 63;
  int grp = lane >> 3, gl = lane & 7;
  int fb = gl * 16;
  float acc[16] = {0.f, 0.f, 0.f, 0.f, 0.f, 0.f, 0.f, 0.f,
                   0.f, 0.f, 0.f, 0.f, 0.f, 0.f, 0.f, 0.f};
  int j0 = off[v], j1 = off[v + 1];
  for (int j = j0 + grp; j < j1; j += 8) {
    int2 e = edata[j];
    float w = __int_as_float(e.y);
    h8 m0 = *(const h8*)&xh[(size_t)e.x * HID + fb];
    h8 m1 = *(const h8*)&xh[(size_t)e.x * HID + fb + 8];
#pragma unroll
    for (int q = 0; q < 8; ++q) {
      acc[q] = fmaf(w, (float)m0[q], acc[q]);
      acc[8 + q] = fmaf(w, (float)m1[q], acc[8 + q]);
    }
  }
#pragma unroll
  for (int q = 0; q < 16; ++q) {
    acc[q] += __shfl_xor(acc[q], 8);
    acc[q] += __shfl_xor(acc[q], 16);
    acc[q] += __shfl_xor(acc[q], 32);
  }
  if (grp == 0) {
    float dv = dinv[v], dv2 = dv * dv;
    h8 s0 = *(const h8*)&xh[(size_t)v * HID + fb];
    h8 s1 = *(const h8*)&xh[(size_t)v * HID + fb + 8];
    h8 o0, o1;
#pragma unroll
    for (int q = 0; q < 8; ++q) {
      float a0 = fmaxf(fmaf(dv2, (float)s0[q], acc[q]) + bias[fb + q], 0.f);
      float a1 = fmaxf(fmaf(dv2, (float)s1[q], acc[8 + q]) + bias[fb + 8 + q], 0.f);
      o0[q] = (_Float16)a0;
      o1[q] = (_Float16)a1;
    }
    *(h8*)&hout[(size_t)v * HID + fb] = o0;
    *(h8*)&hout[(size_t)v * HID + fb + 8] = o1;
  }
}

// ---------------- per-graph node counts ----------------
__global__ __launch_bounds__(256) void k_gcnt(const idx_t* __restrict__ batch,
                                              int* __restrict__ gcnt, int n) {
  __shared__ int h[NGRAPH];
  int tid = threadIdx.x;
  if (tid < NGRAPH) h[tid] = 0;
  __syncthreads();
  int i = blockIdx.x * 256 + tid;
  if (i < n) atomicAdd(&h[batch[i]], 1);
  __syncthreads();
  if (tid < NGRAPH && h[tid]) atomicAdd(&gcnt[tid], h[tid]);
}

// ---------------- segment max+sum pooling (fp16 input, batch sorted) -------
__global__ __launch_bounds__(128) void k_pool(const _Float16* __restrict__ h,
                                              const idx_t* __restrict__ batch,
                                              float* __restrict__ gmax,
                                              float* __restrict__ gsum, int n) {
  int f = threadIdx.x;
  int v0 = blockIdx.x * 128;
  int cur = -1;
  float mx = 0.f, sm = 0.f;
  for (int i = 0; i < 128; ++i) {
    int v = v0 + i;
    if (v >= n) break;
    int g = batch[v];
    if (g != cur) {
      if (cur >= 0) {
        atomicMax((int*)&gmax[cur * HID + f], __float_as_int(mx));  // h>=0
        atomicAdd(&gsum[cur * HID + f], sm);
      }
      cur = g; mx = 0.f; sm = 0.f;
    }
    float val = (float)h[(size_t)v * HID + f];
    mx = fmaxf(mx, val);
    sm += val;
  }
  if (cur >= 0) {
    atomicMax((int*)&gmax[cur * HID + f], __float_as_int(mx));
    atomicAdd(&gsum[cur * HID + f], sm);
  }
}

// ---------------- tiny MLP head (one block) ----------------
__global__ __launch_bounds__(256) void k_mlp(const float* __restrict__ gmax,
                                             const float* __restrict__ gsum,
                                             const int* __restrict__ gcnt,
                                             const float* __restrict__ Wl1,
                                             const float* __restrict__ bl1,
                                             const float* __restrict__ Wl2,
                                             const float* __restrict__ bl2,
                                             const float* __restrict__ Wl3,
                                             const float* __restrict__ bl3,
                                             float* __restrict__ out) {
  __shared__ float G[NGRAPH][2 * HID];
  __shared__ float H1[NGRAPH][HID];
  __shared__ float H2[NGRAPH][HID / 2];
  int t = threadIdx.x;
  for (int i = t; i < NGRAPH * 2 * HID; i += 256) {
    int gi = i >> 8, j = i & 255;
    float val;
    if (j < HID) val = gmax[gi * HID + j];
    else val = gsum[gi * HID + (j - HID)] / fmaxf((float)gcnt[gi], 1.0f);
    G[gi][j] = val;
  }
  __syncthreads();
  for (int i = t; i < NGRAPH * HID; i += 256) {
    int gi = i >> 7, j = i & 127;
    float a = bl1[j];
    for (int k = 0; k < 2 * HID; ++k) a = fmaf(G[gi][k], Wl1[k * HID + j], a);
    H1[gi][j] = fmaxf(a, 0.f);
  }
  __syncthreads();
  {
    int gi = t >> 6, j = t & 63;
    float a = bl2[j];
    for (int k = 0; k < HID; ++k) a = fmaf(H1[gi][k], Wl2[k * 64 + j], a);
    H2[gi][j] = fmaxf(a, 0.f);
  }
  __syncthreads();
  if (t < NGRAPH) {
    float a = bl3[0];
    for (int k = 0; k < 64; ++k) a = fmaf(H2[t][k], Wl3[k], a);
    out[t] = fminf(a, 5.0f);
  }
}

extern "C" void kernel_launch(void* const* d_in, const int* in_sizes, int n_in,
                              void* d_out, int out_size, void* d_ws, size_t ws_size,
                              hipStream_t stream) {
  const float* x   = (const float*)d_in[0];
  const idx_t* ei  = (const idx_t*)d_in[1];
  const idx_t* bat = (const idx_t*)d_in[2];
  const float* W0 = (const float*)d_in[3];  const float* b0 = (const float*)d_in[4];
  const float* W1 = (const float*)d_in[5];  const float* b1 = (const float*)d_in[6];
  const float* W2 = (const float*)d_in[7];  const float* b2 = (const float*)d_in[8];
  const float* Wl1 = (const float*)d_in[9];  const float* bl1 = (const float*)d_in[10];
  const float* Wl2 = (const float*)d_in[11]; const float* bl2 = (const float*)d_in[12];
  const float* Wl3 = (const float*)d_in[13]; const float* bl3 = (const float*)d_in[14];
  float* out = (float*)d_out;

  const int N = in_sizes[2];
  const int E = in_sizes[1] / 2;
  const idx_t* srcv = ei;
  const idx_t* dstv = ei + E;
  const int nb = (N + SC - 1) / SC;

  char* ws = (char*)d_ws;
  size_t o = 0;
  auto alloc = [&](size_t bytes) -> void* {
    void* p = ws + o;
    o = (o + bytes + 255) & ~(size_t)255;
    return p;
  };
  _Float16* xh  = (_Float16*)alloc((size_t)N * HID * 2);  // GEMM out (gathered)
  _Float16* h16 = (_Float16*)alloc((size_t)N * HID * 2);  // agg out
  float* dinv = (float*)alloc((size_t)N * 4);
  int* cnt    = (int*)alloc((size_t)N * 4);
  int* off    = (int*)alloc((size_t)(N + 1) * 4);
  int* fillc  = (int*)alloc((size_t)N * 4);
  int2* edata = (int2*)alloc((size_t)E * 8);
  int* bsum   = (int*)alloc(64 * 4);
  int* boff   = (int*)alloc(64 * 4);
  _Float16* Wh0 = (_Float16*)alloc((size_t)1024 * HID * 2);
  _Float16* Wl0 = (_Float16*)alloc((size_t)1024 * HID * 2);
  _Float16* Wh1 = (_Float16*)alloc((size_t)HID * HID * 2);
  _Float16* Wlo1 = (_Float16*)alloc((size_t)HID * HID * 2);
  _Float16* Wh2 = (_Float16*)alloc((size_t)HID * HID * 2);
  _Float16* Wlo2 = (_Float16*)alloc((size_t)HID * HID * 2);
  float* gmax = (float*)alloc(NGRAPH * HID * 4);
  float* gsum = (float*)alloc(NGRAPH * HID * 4);
  int* gcnt   = (int*)alloc(NGRAPH * 4);

  hipMemsetAsync(cnt, 0, (size_t)N * 4, stream);
  hipMemsetAsync(fillc, 0, (size_t)N * 4, stream);
  hipMemsetAsync(gmax, 0, NGRAPH * HID * 4, stream);
  hipMemsetAsync(gsum, 0, NGRAPH * HID * 4, stream);
  hipMemsetAsync(gcnt, 0, NGRAPH * 4, stream);

  // weight splits, fragment-ordered (tiny)
  k_wsplitf<<<(1024 * HID + 255) / 256, 256, 0, stream>>>(W0, Wh0, Wl0, 1024);
  k_wsplitf<<<(HID * HID + 255) / 256, 256, 0, stream>>>(W1, Wh1, Wlo1, HID);
  k_wsplitf<<<(HID * HID + 255) / 256, 256, 0, stream>>>(W2, Wh2, Wlo2, HID);

  // CSR build
  k_count<<<(E + 255) / 256, 256, 0, stream>>>(dstv, cnt, E);
  k_scan1<<<nb, 256, 0, stream>>>(cnt, bsum, N);
  k_scan2<<<1, 64, 0, stream>>>(bsum, boff, off, nb, N);
  k_scan3<<<nb, 256, 0, stream>>>(cnt, boff, off, dinv, N);
  k_fill<<<(E + 255) / 256, 256, 0, stream>>>(srcv, dstv, off, dinv, fillc, edata, E);

  const int gblk = (N + 63) / 64;   // 782 blocks, 4 waves each (M-split)
  const int ablk = (N + 3) / 4;
  // layer 0: 1024 -> 128 (fp32 in, 3-pass)
  k_gemm8<1024, true><<<gblk, 256, 0, stream>>>(x, Wh0, Wl0, xh, N);
  k_agg16<<<ablk, 256, 0, stream>>>(xh, dinv, off, edata, b0, h16, N);
  // layer 1 (fp16 in, 2-pass)
  k_gemm8<HID, false><<<gblk, 256, 0, stream>>>(h16, Wh1, Wlo1, xh, N);
  k_agg16<<<ablk, 256, 0, stream>>>(xh, dinv, off, edata, b1, h16, N);
  // layer 2
  k_gemm8<HID, false><<<gblk, 256, 0, stream>>>(h16, Wh2, Wlo2, xh, N);
  k_agg16<<<ablk, 256, 0, stream>>>(xh, dinv, off, edata, b2, h16, N);

  // pooling + head
  k_gcnt<<<(N + 255) / 256, 256, 0, stream>>>(bat, gcnt, N);
  k_pool<<<(N + 127) / 128, 128, 0, stream>>>(h16, bat, gmax, gsum, N);
  k_mlp<<<1, 256, 0, stream>>>(gmax, gsum, gcnt, Wl1, bl1, Wl2, bl2, Wl3, bl3, out);
}